// Round 5
// baseline (188.713 us; speedup 1.0000x reference)
//
#include <hip/hip_runtime.h>
#include <math.h>

#define NNODES 10000
#define BATCH  32
#define DDIM   512
#define KSEL   5000
#define EPSV   1e-8f
#define SPAN   125

// Monotone map: float ordering -> unsigned ordering
__device__ __forceinline__ unsigned mapf(float f) {
    unsigned u = __float_as_uint(f);
    return (u & 0x80000000u) ? ~u : (u | 0x80000000u);
}

// K1: score. 256 thr = 4 waves/block. Each block computes w = v/||v|| locally
// (identical order in every block -> bit-identical), then each wave scores 4
// consecutive nodes with w held in registers.
__global__ __launch_bounds__(256) void score_kernel(const float* __restrict__ x,
                                                    const float* __restrict__ v,
                                                    float* __restrict__ raw,
                                                    float* __restrict__ loss_out) {
    __shared__ float wsh[DDIM];
    __shared__ float red[4];
    const int tid = threadIdx.x;
    const int lane = tid & 63, wv = tid >> 6;

    float v1 = v[tid], v2 = v[tid + 256];
    float sq = v1 * v1 + v2 * v2;
    for (int off = 32; off > 0; off >>= 1) sq += __shfl_down(sq, off);
    if (lane == 0) red[wv] = sq;
    __syncthreads();
    float nrm = sqrtf(red[0] + red[1] + red[2] + red[3]) + EPSV;
    wsh[tid] = v1 / nrm;
    wsh[tid + 256] = v2 / nrm;
    __syncthreads();
    if (blockIdx.x == 0 && tid == 0) loss_out[0] = 0.f;  // ready before select kernel

    const float4* wp = (const float4*)wsh;
    const float4 wA = wp[lane], wB = wp[lane + 64];

    const int base = blockIdx.x * 16 + wv * 4;  // first of this wave's 4 nodes
    const float4* xp = (const float4*)(x + (size_t)base * DDIM);

    float4 a0 = xp[0 * 128 + lane], a1 = xp[0 * 128 + lane + 64];
    float4 b0 = xp[1 * 128 + lane], b1 = xp[1 * 128 + lane + 64];
    float4 c0 = xp[2 * 128 + lane], c1 = xp[2 * 128 + lane + 64];
    float4 e0 = xp[3 * 128 + lane], e1 = xp[3 * 128 + lane + 64];

    float d0 = a0.x * wA.x + a0.y * wA.y + a0.z * wA.z + a0.w * wA.w
             + a1.x * wB.x + a1.y * wB.y + a1.z * wB.z + a1.w * wB.w;
    float d1 = b0.x * wA.x + b0.y * wA.y + b0.z * wA.z + b0.w * wA.w
             + b1.x * wB.x + b1.y * wB.y + b1.z * wB.z + b1.w * wB.w;
    float d2 = c0.x * wA.x + c0.y * wA.y + c0.z * wA.z + c0.w * wA.w
             + c1.x * wB.x + c1.y * wB.y + c1.z * wB.z + c1.w * wB.w;
    float d3 = e0.x * wA.x + e0.y * wA.y + e0.z * wA.z + e0.w * wA.w
             + e1.x * wB.x + e1.y * wB.y + e1.z * wB.z + e1.w * wB.w;

    for (int off = 32; off > 0; off >>= 1) {
        d0 += __shfl_down(d0, off);
        d1 += __shfl_down(d1, off);
        d2 += __shfl_down(d2, off);
        d3 += __shfl_down(d3, off);
    }
    if (lane == 0) {
        float4 r; r.x = d0; r.y = d1; r.z = d2; r.w = d3;
        *(float4*)(raw + base) = r;
    }
}

// One radix level: histogram candidates (prefix-matched) into nbins on bits
// [shift .. shift+log2(nbins)), then find bin of the k-th largest.
// res[0] = bin index, res[1] = count strictly above that bin (within candidates).
__device__ void radix_level(const float* __restrict__ s, unsigned* hist, unsigned* segsum,
                            unsigned prefix, int prefshift, int shift, int nbins,
                            unsigned k, unsigned* res, int tid) {
    for (int i = tid; i < nbins; i += 1024) hist[i] = 0;
    __syncthreads();
    for (int i = tid; i < NNODES; i += 1024) {
        unsigned u = mapf(s[i]);
        bool cand = (prefshift >= 32) || ((u >> prefshift) == prefix);
        if (cand) atomicAdd(&hist[(u >> shift) & (unsigned)(nbins - 1)], 1u);
    }
    __syncthreads();
    int nseg = nbins >> 5;
    if (tid < nseg) {
        unsigned ssum = 0;
        for (int j = 0; j < 32; j++) ssum += hist[(tid << 5) + j];
        segsum[tid] = ssum;
    }
    __syncthreads();
    if (tid == 0) {
        unsigned cum = 0;
        int seg = 0;
        for (int i = nseg - 1; i >= 0; i--) {
            if (cum + segsum[i] >= k) { seg = i; break; }
            cum += segsum[i];
        }
        int bin = seg << 5;
        for (int j = 31; j >= 0; j--) {
            unsigned h = hist[(seg << 5) + j];
            if (cum + h >= k) { bin = (seg << 5) + j; break; }
            cum += h;
        }
        res[0] = (unsigned)bin;
        res[1] = cum;
    }
    __syncthreads();
}

// K2: per-batch stats, radix-select K-th largest, loss, compacted (idx, wt) list.
// Also zeroes this batch's pooled output slice.
__global__ __launch_bounds__(1024) void select_kernel(const float* __restrict__ raw,
                                                      int* __restrict__ sel_idx,
                                                      float* __restrict__ sel_wt,
                                                      float* __restrict__ out_pooled,
                                                      float* __restrict__ loss_out) {
    __shared__ float s[NNODES];
    __shared__ unsigned hist[2048];
    __shared__ unsigned segsum[64];
    __shared__ float fredA[16], fredB[16];
    __shared__ unsigned eq_idx[128];
    __shared__ int eq_cnt;
    __shared__ int sel_cnt;
    __shared__ float fb[2];
    __shared__ unsigned res[2];

    const int tid = threadIdx.x;
    const int lane = tid & 63;
    const int wid = tid >> 6;
    const int b = blockIdx.x;
    const float* rb = raw + (size_t)b * NNODES;
    int* sib = sel_idx + (size_t)b * KSEL;
    float* swb = sel_wt + (size_t)b * KSEL;

    for (int i = tid; i < DDIM; i += 1024) out_pooled[(size_t)b * DDIM + i] = 0.f;

    float sum = 0.f, sumsq = 0.f;
    for (int i = tid; i < NNODES; i += 1024) {
        float v = rb[i];
        s[i] = v;
        sum += v; sumsq += v * v;
    }
    for (int off = 32; off > 0; off >>= 1) {
        sum += __shfl_down(sum, off);
        sumsq += __shfl_down(sumsq, off);
    }
    if (lane == 0) { fredA[wid] = sum; fredB[wid] = sumsq; }
    if (tid == 0) { eq_cnt = 0; sel_cnt = 0; }
    __syncthreads();
    if (tid == 0) {
        float ts = 0.f, tq = 0.f;
        for (int i = 0; i < 16; i++) { ts += fredA[i]; tq += fredB[i]; }
        float mu = ts / (float)NNODES;
        float var = tq / (float)NNODES - mu * mu;
        float sd = sqrtf(fmaxf(var, 0.f));
        fb[0] = mu; fb[1] = 1.f / (sd + EPSV);
    }
    __syncthreads();
    const float mu = fb[0], inv = fb[1];

    // 3-level radix select: bits [31:21], [20:10], [9:0]
    radix_level(s, hist, segsum, 0u, 32, 21, 2048, (unsigned)KSEL, res, tid);
    unsigned t1 = res[0];
    unsigned cg = res[1];
    unsigned k1 = (unsigned)KSEL - cg;
    radix_level(s, hist, segsum, t1, 21, 10, 2048, k1, res, tid);
    unsigned t2 = res[0];
    cg += res[1];
    unsigned k2 = k1 - res[1];
    unsigned p2 = (t1 << 11) | t2;
    radix_level(s, hist, segsum, p2, 10, 0, 1024, k2, res, tid);
    unsigned t3 = res[0];
    cg += res[1];
    const unsigned tu = (p2 << 10) | t3;
    const unsigned count_gt = cg;

    // loss + compaction; collect tied-at-threshold indices
    float l = 0.f;
    for (int i = tid; i < NNODES; i += 1024) {
        float v = s[i];
        unsigned m = mapf(v);
        float z = (v - mu) * inv;
        float sig = 1.f / (1.f + expf(-z));
        if (m > tu) {
            l += logf(sig + EPSV);
            int p = atomicAdd(&sel_cnt, 1);
            sib[p] = i; swb[p] = sig;
        } else if (m < tu) {
            l += logf(1.f - sig + EPSV);
        } else {
            int p = atomicAdd(&eq_cnt, 1);
            if (p < 128) eq_idx[p] = (unsigned)i;
        }
    }
    for (int off = 32; off > 0; off >>= 1) l += __shfl_down(l, off);
    if (lane == 0) fredA[wid] = l;
    __syncthreads();
    if (tid == 0) {
        float tl = 0.f;
        for (int i = 0; i < 16; i++) tl += fredA[i];
        int ce = eq_cnt;
        int stored = ce > 128 ? 128 : ce;
        for (int i = 1; i < stored; i++) {  // ties ascending (jax prefers lower idx)
            unsigned key = eq_idx[i]; int j = i - 1;
            while (j >= 0 && eq_idx[j] > key) { eq_idx[j + 1] = eq_idx[j]; j--; }
            eq_idx[j + 1] = key;
        }
        int ne = KSEL - (int)count_gt;
        int sc = sel_cnt;
        for (int p = 0; p < stored; p++) {
            unsigned idx = eq_idx[p];
            float v = s[idx];
            float z = (v - mu) * inv;
            float sig = 1.f / (1.f + expf(-z));
            if (p < ne) { tl += logf(sig + EPSV); sib[sc] = (int)idx; swb[sc] = sig; sc++; }
            else        { tl += logf(1.f - sig + EPSV); }
        }
        if (ce > stored) {  // pathological mass-tie fallback
            float v = s[eq_idx[0]];
            float z = (v - mu) * inv;
            float sig = 1.f / (1.f + expf(-z));
            int extra_sel = ne - stored; if (extra_sel < 0) extra_sel = 0;
            for (int p = 0; p < extra_sel; p++) { sib[sc] = (int)eq_idx[0]; swb[sc] = sig; sc++; }
            tl += (float)((ce - stored) - extra_sel) * logf(1.f - sig + EPSV);
        }
        float loss_b = -tl / (float)NNODES;
        atomicAdd(loss_out, loss_b / (float)BATCH);
    }
}

// K3: pooled[b,:] += (1/K) * sum over a SPAN of the compacted selection list.
// Batches consumed in REVERSE order: the last-scored batches are still
// L3-resident when pool starts; read them before eviction. Plain (allocating)
// loads so hits are actually served from L3.
__global__ __launch_bounds__(128) void pool_kernel(const float* __restrict__ x,
                                                   const int* __restrict__ sel_idx,
                                                   const float* __restrict__ sel_wt,
                                                   float* __restrict__ out) {
    __shared__ int sidx[SPAN];
    __shared__ float swt[SPAN];
    const int spans = KSEL / SPAN;  // 40
    const int b = (BATCH - 1) - blockIdx.x / spans;  // reverse batch order
    const int sp = blockIdx.x % spans;
    const int e0 = sp * SPAN;
    const int tid = threadIdx.x;
    const int* ib = sel_idx + (size_t)b * KSEL + e0;
    const float* wp = sel_wt + (size_t)b * KSEL + e0;
    for (int i = tid; i < SPAN; i += 128) { sidx[i] = ib[i]; swt[i] = wp[i]; }
    __syncthreads();
    const float4* xb = (const float4*)x + (size_t)b * NNODES * (DDIM / 4);
    float ax = 0.f, ay = 0.f, az = 0.f, aw = 0.f;
    #pragma unroll 4
    for (int e = 0; e < SPAN; e++) {
        int n = sidx[e];
        float wt = swt[e];
        float4 xv = xb[(size_t)n * (DDIM / 4) + tid];
        ax += xv.x * wt; ay += xv.y * wt;
        az += xv.z * wt; aw += xv.w * wt;
    }
    const float scale = 1.f / (float)KSEL;
    float* o = out + b * DDIM + tid * 4;
    atomicAdd(o + 0, ax * scale);
    atomicAdd(o + 1, ay * scale);
    atomicAdd(o + 2, az * scale);
    atomicAdd(o + 3, aw * scale);
}

extern "C" void kernel_launch(void* const* d_in, const int* in_sizes, int n_in,
                              void* d_out, int out_size, void* d_ws, size_t ws_size,
                              hipStream_t stream) {
    const float* x = (const float*)d_in[0];   // (B*N, D) fp32
    const float* v = (const float*)d_in[1];   // (D, 1) fp32
    float* out = (float*)d_out;               // pooled (B*D) then loss (1)

    float* raw     = (float*)d_ws;                     // B*N
    int*   sel_idx = (int*)(raw + BATCH * NNODES);     // B*K
    float* sel_wt  = (float*)(sel_idx + BATCH * KSEL); // B*K

    int total = BATCH * NNODES;
    score_kernel<<<total / 16, 256, 0, stream>>>(x, v, raw, out + BATCH * DDIM);
    select_kernel<<<BATCH, 1024, 0, stream>>>(raw, sel_idx, sel_wt, out, out + BATCH * DDIM);
    pool_kernel<<<BATCH * (KSEL / SPAN), 128, 0, stream>>>(x, sel_idx, sel_wt, out);
}